// Round 4
// baseline (87.219 us; speedup 1.0000x reference)
//
#include <hip/hip_runtime.h>
#include <math.h>

#define N_RAYS 131072
#define N_PTS  128
#define FAR_DELTA 1e10f

typedef float vf4 __attribute__((ext_vector_type(4)));

// DPP cross-lane move: result[lane] = valid(src lane) ? src[srclane] : old[lane].
// row_shl:N = 0x100|N (lane i <- lane i+N), row_shr:N = 0x110|N (lane i <- lane i-N).
// DPP rows are 16 lanes — exactly one ray group, so shifts never cross rays.
template<int CTRL>
__device__ __forceinline__ float dpp_mov(float src, float old) {
    return __builtin_bit_cast(float, __builtin_amdgcn_update_dpp(
        __builtin_bit_cast(int, old), __builtin_bit_cast(int, src),
        CTRL, 0xF, 0xF, false));
}

// 16 lanes per ray, 8 consecutive samples per lane, 4 rays per wave, 16 rays per block.
// Feature (60% of bytes, used once) is loaded NON-TEMPORALLY so the 128 MB of
// density+depth stays resident in the 256 MB L3 across replays instead of
// being churned by the 192 MB feature stream.
__global__ __launch_bounds__(256, 4) void volrender_kernel(
    const float* __restrict__ density,
    const float* __restrict__ feature,
    const float* __restrict__ depthv,
    float* __restrict__ out)
{
    const int tid = threadIdx.x;
    const int sub = tid & 15;                     // lane position within ray
    const int ray = blockIdx.x * 16 + (tid >> 4); // 16 rays per 256-thread block

    const size_t sbase = (size_t)ray * N_PTS + sub * 8;

    // Coalesced float4 loads (cached: want these L3-resident).
    const float4 d0 = *reinterpret_cast<const float4*>(depthv + sbase);
    const float4 d1 = *reinterpret_cast<const float4*>(depthv + sbase + 4);
    const float4 g0 = *reinterpret_cast<const float4*>(density + sbase);
    const float4 g1 = *reinterpret_cast<const float4*>(density + sbase + 4);

    // 24 contiguous feature floats per lane (96 B), 6x dwordx4, non-temporal.
    const vf4* fb4 = reinterpret_cast<const vf4*>(feature + (size_t)ray * (N_PTS * 3) + sub * 24);
    vf4 fv[6];
    #pragma unroll
    for (int k = 0; k < 6; ++k) fv[k] = __builtin_nontemporal_load(fb4 + k);
    float ff[24];
    #pragma unroll
    for (int k = 0; k < 6; ++k) {
        ff[4 * k + 0] = fv[k].x; ff[4 * k + 1] = fv[k].y;
        ff[4 * k + 2] = fv[k].z; ff[4 * k + 3] = fv[k].w;
    }

    const float dv[8] = {d0.x, d0.y, d0.z, d0.w, d1.x, d1.y, d1.z, d1.w};
    const float sg[8] = {g0.x, g0.y, g0.z, g0.w, g1.x, g1.y, g1.z, g1.w};

    // deltas: within-lane diffs + first depth of the next lane (row_shl:1).
    const float dn = dpp_mov<0x101>(d0.x, 0.0f);
    float dl[8];
    #pragma unroll
    for (int j = 0; j < 7; ++j) dl[j] = dv[j + 1] - dv[j];
    dl[7] = (sub == 15) ? FAR_DELTA : (dn - dv[7]);

    // t_j = exp(-sigma_j * delta_j); in-lane inclusive products p_j.
    float t[8], p[8];
    #pragma unroll
    for (int j = 0; j < 8; ++j) t[j] = __expf(-sg[j] * dl[j]);
    p[0] = t[0];
    #pragma unroll
    for (int j = 1; j < 8; ++j) p[j] = p[j - 1] * t[j];

    // Cross-lane inclusive product scan of per-lane product (row_shr Kogge-Stone).
    float scan = p[7];
    scan *= dpp_mov<0x111>(scan, 1.0f);
    scan *= dpp_mov<0x112>(scan, 1.0f);
    scan *= dpp_mov<0x114>(scan, 1.0f);
    scan *= dpp_mov<0x118>(scan, 1.0f);
    const float excl = dpp_mov<0x111>(scan, 1.0f);  // exclusive prefix

    // Per-sample T, weights, feature/depth partials.
    float fx = 0.f, fy = 0.f, fz = 0.f, st = 0.f, sd = 0.f;
    #pragma unroll
    for (int j = 0; j < 8; ++j) {
        const float T = (j == 0) ? excl : excl * p[j - 1];
        const float w = fmaf(-T, t[j], T);          // T*(1-t)
        fx = fmaf(w, ff[3 * j + 0], fx);
        fy = fmaf(w, ff[3 * j + 1], fy);
        fz = fmaf(w, ff[3 * j + 2], fz);
        const float ts = (T < 1.0f) ? t[j] : 0.0f;
        st += ts;
        sd = fmaf(ts, dv[j], sd);
    }

    // Cross-lane sum reductions to lane sub==0 (row_shl tree, 0-fill identity).
    #define RED16(x)                 \
        x += dpp_mov<0x108>(x, 0.f); \
        x += dpp_mov<0x104>(x, 0.f); \
        x += dpp_mov<0x102>(x, 0.f); \
        x += dpp_mov<0x101>(x, 0.f);
    RED16(fx) RED16(fy) RED16(fz) RED16(st) RED16(sd)
    #undef RED16

    if (sub == 0) {
        out[(size_t)ray * 3 + 0] = fx;
        out[(size_t)ray * 3 + 1] = fy;
        out[(size_t)ray * 3 + 2] = fz;
        const float dep = sd / st;
        out[(size_t)N_RAYS * 3 + ray] = (dep == 0.0f) ? INFINITY : dep;
    }
}

extern "C" void kernel_launch(void* const* d_in, const int* in_sizes, int n_in,
                              void* d_out, int out_size, void* d_ws, size_t ws_size,
                              hipStream_t stream) {
    const float* density = (const float*)d_in[0];
    const float* feature = (const float*)d_in[1];
    const float* depthv  = (const float*)d_in[2];
    float* out = (float*)d_out;

    const int grid = N_RAYS / 16;   // 8192 blocks, 16 rays per block
    volrender_kernel<<<grid, 256, 0, stream>>>(density, feature, depthv, out);
}

// Round 5
// 64.822 us; speedup vs baseline: 1.3455x; 1.3455x over previous
//
#include <hip/hip_runtime.h>
#include <math.h>

#define N_RAYS 131072
#define N_PTS  128
#define FAR_DELTA 1e10f

// One 64-lane wave per ray; lane i owns samples 2i and 2i+1.
// All global reads are coalesced (float2). Cumprod over 128 samples =
// per-lane product + 6-step shfl_up inclusive product scan across the wave.
// Session-best structure (65.6 us); r3 (prefetch) and r4 (nontemporal)
// variants both regressed — memory-system-limited at ~4.9 TB/s effective.
__global__ __launch_bounds__(256) void volrender_kernel(
    const float* __restrict__ density,
    const float* __restrict__ feature,
    const float* __restrict__ depthv,
    float* __restrict__ out)
{
    const int lane = threadIdx.x & 63;
    const int ray  = blockIdx.x * 4 + (threadIdx.x >> 6);
    if (ray >= N_RAYS) return;

    const size_t rbase = (size_t)ray * N_PTS + 2 * lane;
    const float2 dv = *reinterpret_cast<const float2*>(depthv  + rbase);
    const float2 sg = *reinterpret_cast<const float2*>(density + rbase);

    const float* fb = feature + (size_t)ray * N_PTS * 3 + 6 * lane;
    const float2 fA = *reinterpret_cast<const float2*>(fb);      // f0.x f0.y
    const float2 fB = *reinterpret_cast<const float2*>(fb + 2);  // f0.z f1.x
    const float2 fC = *reinterpret_cast<const float2*>(fb + 4);  // f1.y f1.z

    // deltas: need depth of next sample; sample 2i+2 lives in lane i+1.
    const float dnext  = __shfl_down(dv.x, 1);
    const float delta0 = dv.y - dv.x;
    const float delta1 = (lane == 63) ? FAR_DELTA : (dnext - dv.y);

    const float t0 = __expf(-sg.x * delta0);
    const float t1 = __expf(-sg.y * delta1);

    // Inclusive product scan of per-lane product p = t0*t1 across 64 lanes.
    float scan = t0 * t1;
    #pragma unroll
    for (int off = 1; off < 64; off <<= 1) {
        const float v = __shfl_up(scan, off);
        if (lane >= off) scan *= v;
    }
    // Exclusive prefix: T at sample 2i.
    float excl = __shfl_up(scan, 1);
    if (lane == 0) excl = 1.0f;
    const float T0 = excl;
    const float T1 = excl * t0;

    // Alpha-compositing weights and RGB partial sums.
    const float w0 = T0 * (1.0f - t0);
    const float w1 = T1 * (1.0f - t1);
    float fx = w0 * fA.x + w1 * fB.y;
    float fy = w0 * fA.y + w1 * fC.x;
    float fz = w0 * fB.x + w1 * fC.y;

    // Depth estimate: keep samples with T < 1; depth = sum(t*dv)/sum(t).
    const float ts0 = (T0 < 1.0f) ? t0 : 0.0f;
    const float ts1 = (T1 < 1.0f) ? t1 : 0.0f;
    float st = ts0 + ts1;
    float sd = ts0 * dv.x + ts1 * dv.y;

    // Wave-wide butterfly reduction of the 5 partials.
    #pragma unroll
    for (int off = 32; off > 0; off >>= 1) {
        fx += __shfl_xor(fx, off);
        fy += __shfl_xor(fy, off);
        fz += __shfl_xor(fz, off);
        st += __shfl_xor(st, off);
        sd += __shfl_xor(sd, off);
    }

    if (lane == 0) {
        out[(size_t)ray * 3 + 0] = fx;
        out[(size_t)ray * 3 + 1] = fy;
        out[(size_t)ray * 3 + 2] = fz;
        const float dep = sd / st;
        out[(size_t)N_RAYS * 3 + ray] = (dep == 0.0f) ? INFINITY : dep;
    }
}

extern "C" void kernel_launch(void* const* d_in, const int* in_sizes, int n_in,
                              void* d_out, int out_size, void* d_ws, size_t ws_size,
                              hipStream_t stream) {
    const float* density = (const float*)d_in[0];
    const float* feature = (const float*)d_in[1];
    const float* depthv  = (const float*)d_in[2];
    float* out = (float*)d_out;

    const int rays_per_block = 4;                 // 256 threads = 4 waves
    const int grid = N_RAYS / rays_per_block;     // 32768 blocks
    volrender_kernel<<<grid, 256, 0, stream>>>(density, feature, depthv, out);
}